// Round 2
// baseline (319.526 us; speedup 1.0000x reference)
//
#include <hip/hip_runtime.h>
#include <hip/hip_bf16.h>

typedef __bf16 bf16;
typedef __attribute__((ext_vector_type(8))) __bf16 bf16x8;
typedef __attribute__((ext_vector_type(4))) float f32x4;

#define MFMA16(a, b, c) __builtin_amdgcn_mfma_f32_16x16x32_bf16(a, b, c, 0, 0, 0)

__device__ inline bf16x8 cvt8(const float* p) {
    f32x4 lo = *(const f32x4*)p;
    f32x4 hi = *(const f32x4*)(p + 4);
    bf16x8 r;
    r[0] = (bf16)lo[0]; r[1] = (bf16)lo[1]; r[2] = (bf16)lo[2]; r[3] = (bf16)lo[3];
    r[4] = (bf16)hi[0]; r[5] = (bf16)hi[1]; r[6] = (bf16)hi[2]; r[7] = (bf16)hi[3];
    return r;
}

// ---------------- Kernel 1: all 8 projections (x @ W^T + b, optional l2norm) ----------
// Wave = one 16-row tile x 96 cols.  K=512 in 16 steps of 32.
// A-frag: row = lane&15, k = quad*8+j (row-major x).  B-frag: W row (out col) = lane&15.
// C/D: col = lane&15, row = quad*4 + reg.

struct ProjParams {
    const float* src[8];
    const float* W[8];
    const float* B[8];
    void* dst[8];
};

__global__ __launch_bounds__(256) void proj_kernel(ProjParams p) {
    int wid  = (blockIdx.x << 2) + (threadIdx.x >> 6);
    int lane = threadIdx.x & 63;
    int m = lane & 15, quad = lane >> 4;

    // jobs: 0:t 1:d 2:v 3:Q 4:K 5:V 6:t_tok 7:v_pat ; tiles: 4,4,4,512,512,512,512,784
    int job = 0, tile;
    {
        const int pref1 = 4, pref2 = 8, pref3 = 12, pref4 = 524, pref5 = 1036,
                  pref6 = 1548, pref7 = 2060;
        int base = 0;
        if (wid >= pref1) { job = 1; base = pref1; }
        if (wid >= pref2) { job = 2; base = pref2; }
        if (wid >= pref3) { job = 3; base = pref3; }
        if (wid >= pref4) { job = 4; base = pref4; }
        if (wid >= pref5) { job = 5; base = pref5; }
        if (wid >= pref6) { job = 6; base = pref6; }
        if (wid >= pref7) { job = 7; base = pref7; }
        tile = wid - base;
    }
    const float* X  = p.src[job];
    const float* W  = p.W[job];
    const float* Bv = p.B[job];
    int row0 = tile << 4;

    f32x4 acc[6] = {};
    const float* xrow = X + (size_t)(row0 + m) * 512 + quad * 8;
    const float* wrow = W + (size_t)m * 512 + quad * 8;
    #pragma unroll 4
    for (int kk = 0; kk < 512; kk += 32) {
        bf16x8 a = cvt8(xrow + kk);
        #pragma unroll
        for (int nt = 0; nt < 6; nt++) {
            bf16x8 b = cvt8(wrow + nt * (16 * 512) + kk);
            acc[nt] = MFMA16(a, b, acc[nt]);
        }
    }
    #pragma unroll
    for (int nt = 0; nt < 6; nt++) {
        float bb = Bv[nt * 16 + m];
        acc[nt][0] += bb; acc[nt][1] += bb; acc[nt][2] += bb; acc[nt][3] += bb;
    }
    bool norm = (job < 3) || (job >= 6);
    if (norm) {
        #pragma unroll
        for (int r = 0; r < 4; r++) {
            float ss = 0.0f;
            #pragma unroll
            for (int nt = 0; nt < 6; nt++) ss += acc[nt][r] * acc[nt][r];
            ss += __shfl_xor(ss, 1); ss += __shfl_xor(ss, 2);
            ss += __shfl_xor(ss, 4); ss += __shfl_xor(ss, 8);
            float inv = 1.0f / fmaxf(sqrtf(ss), 1e-6f);
            #pragma unroll
            for (int nt = 0; nt < 6; nt++) acc[nt][r] *= inv;
        }
    }
    if (job < 3) {
        float* dst = (float*)p.dst[job];
        #pragma unroll
        for (int r = 0; r < 4; r++)
            #pragma unroll
            for (int nt = 0; nt < 6; nt++)
                dst[(size_t)(row0 + quad * 4 + r) * 96 + nt * 16 + m] = acc[nt][r];
    } else {
        bf16* dst = (bf16*)p.dst[job];
        #pragma unroll
        for (int r = 0; r < 4; r++)
            #pragma unroll
            for (int nt = 0; nt < 6; nt++)
                dst[(size_t)(row0 + quad * 4 + r) * 96 + nt * 16 + m] = (bf16)acc[nt][r];
    }
}

// ---------------- Kernel 2: TGL attention per (b,c) pair ----------------
// S = Q_b K_c^T / sqrt(96); softmax over k; w[k] = sum_q attn[q,k];
// ctx[h] = (1/128) sum_k w[k] V_c[k,h]; LN; l2n; dot with d_b.

__global__ __launch_bounds__(256) void attn_kernel(
    const bf16* __restrict__ Qg, const bf16* __restrict__ Kg, const bf16* __restrict__ Vg,
    const float* __restrict__ dvec, const float* __restrict__ ln_g, const float* __restrict__ ln_b,
    float* __restrict__ S_TGL)
{
    int b = blockIdx.x >> 6, c = blockIdx.x & 63;
    int tid = threadIdx.x, lane = tid & 63, w = tid >> 6;
    int m = lane & 15, quad = lane >> 4;
    const bf16* Q = Qg + (size_t)b * (128 * 96);
    const bf16* K = Kg + (size_t)c * (128 * 96);
    const bf16* V = Vg + (size_t)c * (128 * 96);

    f32x4 acc[2][8] = {};
    #pragma unroll
    for (int kk = 0; kk < 96; kk += 32) {
        bf16x8 a0 = *(const bf16x8*)(Q + (size_t)(w * 32 + m) * 96 + kk + quad * 8);
        bf16x8 a1 = *(const bf16x8*)(Q + (size_t)(w * 32 + 16 + m) * 96 + kk + quad * 8);
        #pragma unroll
        for (int nt = 0; nt < 8; nt++) {
            bf16x8 bb = *(const bf16x8*)(K + (size_t)(nt * 16 + m) * 96 + kk + quad * 8);
            acc[0][nt] = MFMA16(a0, bb, acc[0][nt]);
            acc[1][nt] = MFMA16(a1, bb, acc[1][nt]);
        }
    }
    const float sc = 0.10206207261596575f;  // 1/sqrt(96)
    float wpart[8];
    #pragma unroll
    for (int nt = 0; nt < 8; nt++) wpart[nt] = 0.0f;
    #pragma unroll
    for (int mt = 0; mt < 2; mt++) {
        #pragma unroll
        for (int r = 0; r < 4; r++) {
            float tv[8]; float mx = -3.4e38f;
            #pragma unroll
            for (int nt = 0; nt < 8; nt++) { tv[nt] = acc[mt][nt][r] * sc; mx = fmaxf(mx, tv[nt]); }
            mx = fmaxf(mx, __shfl_xor(mx, 1)); mx = fmaxf(mx, __shfl_xor(mx, 2));
            mx = fmaxf(mx, __shfl_xor(mx, 4)); mx = fmaxf(mx, __shfl_xor(mx, 8));
            float s = 0.0f;
            #pragma unroll
            for (int nt = 0; nt < 8; nt++) { tv[nt] = __expf(tv[nt] - mx); s += tv[nt]; }
            s += __shfl_xor(s, 1); s += __shfl_xor(s, 2);
            s += __shfl_xor(s, 4); s += __shfl_xor(s, 8);
            float inv = 1.0f / s;
            #pragma unroll
            for (int nt = 0; nt < 8; nt++) wpart[nt] += tv[nt] * inv;
        }
    }
    #pragma unroll
    for (int nt = 0; nt < 8; nt++) {
        wpart[nt] += __shfl_xor(wpart[nt], 16);
        wpart[nt] += __shfl_xor(wpart[nt], 32);
    }
    __shared__ float wsum4[4][128];
    __shared__ float wk[128];
    __shared__ float ctx[96];
    if (lane < 16) {
        #pragma unroll
        for (int nt = 0; nt < 8; nt++) wsum4[w][nt * 16 + lane] = wpart[nt];
    }
    __syncthreads();
    if (tid < 128) wk[tid] = wsum4[0][tid] + wsum4[1][tid] + wsum4[2][tid] + wsum4[3][tid];
    __syncthreads();
    if (tid < 96) {
        float a = 0.0f;
        for (int k = 0; k < 128; k++) a += wk[k] * (float)V[(size_t)k * 96 + tid];
        ctx[tid] = a * (1.0f / 128.0f);
    }
    __syncthreads();
    if (w == 0) {
        float x0 = ctx[lane];
        float x1 = (lane < 32) ? ctx[64 + lane] : 0.0f;
        float s = x0 + x1;
        #pragma unroll
        for (int d = 1; d < 64; d <<= 1) s += __shfl_xor(s, d);
        float mean = s * (1.0f / 96.0f);
        float e0 = x0 - mean;
        float e1 = (lane < 32) ? (x1 - mean) : 0.0f;
        float q = e0 * e0 + e1 * e1;
        #pragma unroll
        for (int d = 1; d < 64; d <<= 1) q += __shfl_xor(q, d);
        float rstd = rsqrtf(q * (1.0f / 96.0f) + 1e-5f);
        float y0 = e0 * rstd * ln_g[lane] + ln_b[lane];
        float y1 = 0.0f;
        if (lane < 32) y1 = e1 * rstd * ln_g[64 + lane] + ln_b[64 + lane];
        const float* db = dvec + b * 96;
        float dot = y0 * db[lane] + ((lane < 32) ? y1 * db[64 + lane] : 0.0f);
        float ss = y0 * y0 + y1 * y1;
        #pragma unroll
        for (int d = 1; d < 64; d <<= 1) { dot += __shfl_xor(dot, d); ss += __shfl_xor(ss, d); }
        if (lane == 0) S_TGL[blockIdx.x] = dot / fmaxf(sqrtf(ss), 1e-6f);
    }
}

// ---------------- Kernel 3: CLL max-sim per (b,c) pair ----------------
// sim = t_tok_b (128x96) @ v_pat_c^T (rows 196, padded tiles clamp to row 195 -> dup rows
// can't change the max). Block max -> S_CLL.

__global__ __launch_bounds__(256) void cll_kernel(
    const bf16* __restrict__ Tt, const bf16* __restrict__ Vp, float* __restrict__ S_CLL)
{
    int b = blockIdx.x >> 6, c = blockIdx.x & 63;
    int tid = threadIdx.x, lane = tid & 63, w = tid >> 6;
    int m = lane & 15, quad = lane >> 4;
    const bf16* T = Tt + (size_t)b * (128 * 96);
    const bf16* P = Vp + (size_t)c * (196 * 96);

    int rofs[13];
    #pragma unroll
    for (int nt = 0; nt < 13; nt++) {
        int r = nt * 16 + m; if (r > 195) r = 195;
        rofs[nt] = r * 96;
    }
    f32x4 acc[2][13] = {};
    #pragma unroll
    for (int kk = 0; kk < 96; kk += 32) {
        bf16x8 a0 = *(const bf16x8*)(T + (size_t)(w * 32 + m) * 96 + kk + quad * 8);
        bf16x8 a1 = *(const bf16x8*)(T + (size_t)(w * 32 + 16 + m) * 96 + kk + quad * 8);
        #pragma unroll
        for (int nt = 0; nt < 13; nt++) {
            bf16x8 bb = *(const bf16x8*)(P + rofs[nt] + kk + quad * 8);
            acc[0][nt] = MFMA16(a0, bb, acc[0][nt]);
            acc[1][nt] = MFMA16(a1, bb, acc[1][nt]);
        }
    }
    float mx = -3.4e38f;
    #pragma unroll
    for (int mt = 0; mt < 2; mt++)
        #pragma unroll
        for (int nt = 0; nt < 13; nt++)
            #pragma unroll
            for (int r = 0; r < 4; r++) mx = fmaxf(mx, acc[mt][nt][r]);
    #pragma unroll
    for (int d = 1; d < 64; d <<= 1) mx = fmaxf(mx, __shfl_xor(mx, d));
    __shared__ float red[4];
    if (lane == 0) red[w] = mx;
    __syncthreads();
    if (tid == 0) S_CLL[blockIdx.x] = fmaxf(fmaxf(red[0], red[1]), fmaxf(red[2], red[3]));
}

// ---------------- Kernel 4: final combine ----------------

__global__ __launch_bounds__(64) void final_kernel(
    const float* __restrict__ t, const float* __restrict__ d, const float* __restrict__ v,
    const float* __restrict__ S_TGL, const float* __restrict__ S_CLL, float* __restrict__ out)
{
    int i = blockIdx.x, j = threadIdx.x;
    __shared__ float ti[96];
    if (j < 64) ti[j] = t[i * 96 + j];
    if (j < 32) ti[64 + j] = t[i * 96 + 64 + j];
    __syncthreads();
    float tg = 0.0f, cg = 0.0f;
    const float* dj = d + j * 96;
    const float* vj = v + j * 96;
    #pragma unroll 8
    for (int h = 0; h < 96; h++) { float th = ti[h]; tg += th * dj[h]; cg += th * vj[h]; }
    float res = 0.5f * (tg + S_TGL[i * 64 + j]) + 0.5f * (cg + S_CLL[i * 64 + j]);
    out[i * 64 + j] = res;
}

// ---------------- launch ----------------

extern "C" void kernel_launch(void* const* d_in, const int* in_sizes, int n_in,
                              void* d_out, int out_size, void* d_ws, size_t ws_size,
                              hipStream_t stream)
{
    (void)in_sizes; (void)n_in; (void)out_size; (void)ws_size;
    const float* z_d_cls   = (const float*)d_in[0];
    const float* Z_d_tok   = (const float*)d_in[1];
    const float* z_t_cls   = (const float*)d_in[2];
    const float* Z_t_tok   = (const float*)d_in[3];
    const float* z_v_cls   = (const float*)d_in[4];
    const float* Z_v_patch = (const float*)d_in[5];

    char* ws = (char*)d_ws;
    float* t     = (float*)(ws + 0);          // 64*96 f32
    float* d     = (float*)(ws + 24576);
    float* v     = (float*)(ws + 49152);
    float* S_TGL = (float*)(ws + 73728);      // 4096 f32
    float* S_CLL = (float*)(ws + 90112);
    bf16* Qb = (bf16*)(ws + 106496);                 // 8192*96 bf16
    bf16* Kb = (bf16*)(ws + 106496 + 1572864);
    bf16* Vb = (bf16*)(ws + 106496 + 2 * 1572864);
    bf16* Tt = (bf16*)(ws + 106496 + 3 * 1572864);
    bf16* Vp = (bf16*)(ws + 106496 + 4 * 1572864);   // 12544*96 bf16

    ProjParams pp;
    pp.src[0] = z_t_cls;   pp.W[0] = (const float*)d_in[6];  pp.B[0] = (const float*)d_in[7];  pp.dst[0] = t;
    pp.src[1] = z_d_cls;   pp.W[1] = (const float*)d_in[8];  pp.B[1] = (const float*)d_in[9];  pp.dst[1] = d;
    pp.src[2] = z_v_cls;   pp.W[2] = (const float*)d_in[10]; pp.B[2] = (const float*)d_in[11]; pp.dst[2] = v;
    pp.src[3] = Z_d_tok;   pp.W[3] = (const float*)d_in[16]; pp.B[3] = (const float*)d_in[17]; pp.dst[3] = Qb;
    pp.src[4] = Z_t_tok;   pp.W[4] = (const float*)d_in[18]; pp.B[4] = (const float*)d_in[19]; pp.dst[4] = Kb;
    pp.src[5] = Z_t_tok;   pp.W[5] = (const float*)d_in[20]; pp.B[5] = (const float*)d_in[21]; pp.dst[5] = Vb;
    pp.src[6] = Z_t_tok;   pp.W[6] = (const float*)d_in[12]; pp.B[6] = (const float*)d_in[13]; pp.dst[6] = Tt;
    pp.src[7] = Z_v_patch; pp.W[7] = (const float*)d_in[14]; pp.B[7] = (const float*)d_in[15]; pp.dst[7] = Vp;

    hipLaunchKernelGGL(proj_kernel, dim3(711), dim3(256), 0, stream, pp);
    hipLaunchKernelGGL(attn_kernel, dim3(4096), dim3(256), 0, stream,
                       (const bf16*)Qb, (const bf16*)Kb, (const bf16*)Vb,
                       (const float*)d, (const float*)d_in[22], (const float*)d_in[23], S_TGL);
    hipLaunchKernelGGL(cll_kernel, dim3(4096), dim3(256), 0, stream,
                       (const bf16*)Tt, (const bf16*)Vp, S_CLL);
    hipLaunchKernelGGL(final_kernel, dim3(64), dim3(64), 0, stream,
                       (const float*)t, (const float*)d, (const float*)v,
                       (const float*)S_TGL, (const float*)S_CLL, (float*)d_out);
}

// Round 3
// 254.072 us; speedup vs baseline: 1.2576x; 1.2576x over previous
//
#include <hip/hip_runtime.h>
#include <hip/hip_bf16.h>

typedef __bf16 bf16;
typedef __attribute__((ext_vector_type(8))) __bf16 bf16x8;
typedef __attribute__((ext_vector_type(4))) float f32x4;
typedef __attribute__((ext_vector_type(4))) unsigned int uint4v;

#define MFMA16(a, b, c) __builtin_amdgcn_mfma_f32_16x16x32_bf16(a, b, c, 0, 0, 0)

__device__ inline bf16x8 cvt8(const float* p) {
    f32x4 lo = *(const f32x4*)p;
    f32x4 hi = *(const f32x4*)(p + 4);
    bf16x8 r;
    r[0] = (bf16)lo[0]; r[1] = (bf16)lo[1]; r[2] = (bf16)lo[2]; r[3] = (bf16)lo[3];
    r[4] = (bf16)hi[0]; r[5] = (bf16)hi[1]; r[6] = (bf16)hi[2]; r[7] = (bf16)hi[3];
    return r;
}

// ---------------- Kernel 0: convert all 8 weight matrices fp32 -> bf16 ----------------
// 8 jobs x 96x512 = 49152 elems each; 48 blocks/job, 4 elems/thread.

struct WPtrs { const float* W[8]; };

__global__ __launch_bounds__(256) void cvtw_kernel(WPtrs wp, bf16* __restrict__ Wb) {
    int j   = blockIdx.x / 48;
    int blk = blockIdx.x - j * 48;
    int idx = (blk * 256 + threadIdx.x) * 4;
    f32x4 v = *(const f32x4*)(wp.W[j] + idx);
    bf16* dst = Wb + j * 49152 + idx;
    dst[0] = (bf16)v[0]; dst[1] = (bf16)v[1]; dst[2] = (bf16)v[2]; dst[3] = (bf16)v[3];
}

// ---------------- Kernel 1: all 8 projections (x @ W^T + b, optional l2norm) ----------
// Wave = TWO 16-row tiles x 96 cols (B-frag reuse).  K=512 in 16 steps of 32.
// A: fp32 load + cvt (X read exactly once).  B: bf16 from Wb (L2-resident).
// C/D: col = lane&15, row = quad*4 + reg.

struct ProjParams {
    const float* src[8];
    const float* B[8];
    void* dst[8];
    const bf16* Wb;
};

__global__ __launch_bounds__(256, 3) void proj_kernel(ProjParams p) {
    int wid  = (blockIdx.x << 2) + (threadIdx.x >> 6);
    if (wid >= 1422) return;
    int lane = threadIdx.x & 63;
    int m = lane & 15, quad = lane >> 4;

    // jobs: 0:t 1:d 2:v 3:Q 4:K 5:V 6:t_tok 7:v_pat
    // wave counts (2 tiles each): 2,2,2,256,256,256,256,392 ; cum: 2,4,6,262,518,774,1030,1422
    int job = 0, base = 0;
    if (wid >= 2)    { job = 1; base = 2; }
    if (wid >= 4)    { job = 2; base = 4; }
    if (wid >= 6)    { job = 3; base = 6; }
    if (wid >= 262)  { job = 4; base = 262; }
    if (wid >= 518)  { job = 5; base = 518; }
    if (wid >= 774)  { job = 6; base = 774; }
    if (wid >= 1030) { job = 7; base = 1030; }
    int wtile = wid - base;
    int r0 = wtile << 5;   // 32 rows per wave

    const float* X  = p.src[job];
    const bf16*  wb = p.Wb + job * 49152 + (size_t)m * 512 + quad * 8;
    const float* x0 = X + (size_t)(r0 + m) * 512 + quad * 8;
    const float* x1 = x0 + 16 * 512;

    f32x4 acc[2][6] = {};
    #pragma unroll 4
    for (int kk = 0; kk < 512; kk += 32) {
        bf16x8 a0 = cvt8(x0 + kk);
        bf16x8 a1 = cvt8(x1 + kk);
        #pragma unroll
        for (int nt = 0; nt < 6; nt++) {
            bf16x8 b = *(const bf16x8*)(wb + nt * 8192 + kk);
            acc[0][nt] = MFMA16(a0, b, acc[0][nt]);
            acc[1][nt] = MFMA16(a1, b, acc[1][nt]);
        }
    }
    const float* Bv = p.B[job];
    bool norm = (job < 3) || (job >= 6);
    #pragma unroll
    for (int t2 = 0; t2 < 2; t2++) {
        int row0 = r0 + t2 * 16;
        f32x4* a = acc[t2];
        #pragma unroll
        for (int nt = 0; nt < 6; nt++) {
            float bb = Bv[nt * 16 + m];
            a[nt][0] += bb; a[nt][1] += bb; a[nt][2] += bb; a[nt][3] += bb;
        }
        if (norm) {
            #pragma unroll
            for (int r = 0; r < 4; r++) {
                float ss = 0.0f;
                #pragma unroll
                for (int nt = 0; nt < 6; nt++) ss += a[nt][r] * a[nt][r];
                ss += __shfl_xor(ss, 1); ss += __shfl_xor(ss, 2);
                ss += __shfl_xor(ss, 4); ss += __shfl_xor(ss, 8);
                float inv = 1.0f / fmaxf(sqrtf(ss), 1e-6f);
                #pragma unroll
                for (int nt = 0; nt < 6; nt++) a[nt][r] *= inv;
            }
        }
        if (job < 3) {
            float* dst = (float*)p.dst[job];
            #pragma unroll
            for (int r = 0; r < 4; r++)
                #pragma unroll
                for (int nt = 0; nt < 6; nt++)
                    dst[(size_t)(row0 + quad * 4 + r) * 96 + nt * 16 + m] = a[nt][r];
        } else {
            bf16* dst = (bf16*)p.dst[job];
            #pragma unroll
            for (int r = 0; r < 4; r++)
                #pragma unroll
                for (int nt = 0; nt < 6; nt++)
                    dst[(size_t)(row0 + quad * 4 + r) * 96 + nt * 16 + m] = (bf16)a[nt][r];
        }
    }
}

// ---------------- Kernel 2: TGL attention per (b,c) pair ----------------
// K_c staged in LDS once per block; 4 waves split Q rows.
// S = Q_b K_c^T / sqrt(96); softmax over k; w[k] = sum_q attn[q,k];
// ctx[h] = (1/128) sum_k w[k] V_c[k,h]; LN; l2n; dot with d_b.

__global__ __launch_bounds__(256, 3) void attn_kernel(
    const bf16* __restrict__ Qg, const bf16* __restrict__ Kg, const bf16* __restrict__ Vg,
    const float* __restrict__ dvec, const float* __restrict__ ln_g, const float* __restrict__ ln_b,
    float* __restrict__ S_TGL)
{
    int b = blockIdx.x >> 6, c = blockIdx.x & 63;
    int tid = threadIdx.x, lane = tid & 63, w = tid >> 6;
    int m = lane & 15, quad = lane >> 4;
    const bf16* Q = Qg + (size_t)b * (128 * 96);
    const bf16* K = Kg + (size_t)c * (128 * 96);
    const bf16* V = Vg + (size_t)c * (128 * 96);

    __shared__ __align__(16) bf16 Klds[128 * 96];
    #pragma unroll
    for (int ch = 0; ch < 6; ch++) {
        int idx = (ch * 256 + tid) * 8;
        *(uint4v*)(Klds + idx) = *(const uint4v*)(K + idx);
    }
    __syncthreads();

    f32x4 acc[2][8] = {};
    #pragma unroll
    for (int kk = 0; kk < 96; kk += 32) {
        bf16x8 a0 = *(const bf16x8*)(Q + (size_t)(w * 32 + m) * 96 + kk + quad * 8);
        bf16x8 a1 = *(const bf16x8*)(Q + (size_t)(w * 32 + 16 + m) * 96 + kk + quad * 8);
        #pragma unroll
        for (int nt = 0; nt < 8; nt++) {
            bf16x8 bb = *(const bf16x8*)(Klds + (nt * 16 + m) * 96 + kk + quad * 8);
            acc[0][nt] = MFMA16(a0, bb, acc[0][nt]);
            acc[1][nt] = MFMA16(a1, bb, acc[1][nt]);
        }
    }
    const float sc = 0.10206207261596575f;  // 1/sqrt(96)
    float wpart[8];
    #pragma unroll
    for (int nt = 0; nt < 8; nt++) wpart[nt] = 0.0f;
    #pragma unroll
    for (int mt = 0; mt < 2; mt++) {
        #pragma unroll
        for (int r = 0; r < 4; r++) {
            float tv[8]; float mx = -3.4e38f;
            #pragma unroll
            for (int nt = 0; nt < 8; nt++) { tv[nt] = acc[mt][nt][r] * sc; mx = fmaxf(mx, tv[nt]); }
            mx = fmaxf(mx, __shfl_xor(mx, 1)); mx = fmaxf(mx, __shfl_xor(mx, 2));
            mx = fmaxf(mx, __shfl_xor(mx, 4)); mx = fmaxf(mx, __shfl_xor(mx, 8));
            float s = 0.0f;
            #pragma unroll
            for (int nt = 0; nt < 8; nt++) { tv[nt] = __expf(tv[nt] - mx); s += tv[nt]; }
            s += __shfl_xor(s, 1); s += __shfl_xor(s, 2);
            s += __shfl_xor(s, 4); s += __shfl_xor(s, 8);
            float inv = 1.0f / s;
            #pragma unroll
            for (int nt = 0; nt < 8; nt++) wpart[nt] += tv[nt] * inv;
        }
    }
    #pragma unroll
    for (int nt = 0; nt < 8; nt++) {
        wpart[nt] += __shfl_xor(wpart[nt], 16);
        wpart[nt] += __shfl_xor(wpart[nt], 32);
    }
    __shared__ float wsum4[4][128];
    __shared__ float wk[128];
    __shared__ float ctx[96];
    if (lane < 16) {
        #pragma unroll
        for (int nt = 0; nt < 8; nt++) wsum4[w][nt * 16 + lane] = wpart[nt];
    }
    __syncthreads();
    if (tid < 128) wk[tid] = wsum4[0][tid] + wsum4[1][tid] + wsum4[2][tid] + wsum4[3][tid];
    __syncthreads();
    if (tid < 96) {
        float a = 0.0f;
        for (int k = 0; k < 128; k++) a += wk[k] * (float)V[(size_t)k * 96 + tid];
        ctx[tid] = a * (1.0f / 128.0f);
    }
    __syncthreads();
    if (w == 0) {
        float x0 = ctx[lane];
        float x1 = (lane < 32) ? ctx[64 + lane] : 0.0f;
        float s = x0 + x1;
        #pragma unroll
        for (int d = 1; d < 64; d <<= 1) s += __shfl_xor(s, d);
        float mean = s * (1.0f / 96.0f);
        float e0 = x0 - mean;
        float e1 = (lane < 32) ? (x1 - mean) : 0.0f;
        float q = e0 * e0 + e1 * e1;
        #pragma unroll
        for (int d = 1; d < 64; d <<= 1) q += __shfl_xor(q, d);
        float rstd = rsqrtf(q * (1.0f / 96.0f) + 1e-5f);
        float y0 = e0 * rstd * ln_g[lane] + ln_b[lane];
        float y1 = 0.0f;
        if (lane < 32) y1 = e1 * rstd * ln_g[64 + lane] + ln_b[64 + lane];
        const float* db = dvec + b * 96;
        float dot = y0 * db[lane] + ((lane < 32) ? y1 * db[64 + lane] : 0.0f);
        float ss = y0 * y0 + y1 * y1;
        #pragma unroll
        for (int d = 1; d < 64; d <<= 1) { dot += __shfl_xor(dot, d); ss += __shfl_xor(ss, d); }
        if (lane == 0) S_TGL[blockIdx.x] = dot / fmaxf(sqrtf(ss), 1e-6f);
    }
}

// ---------------- Kernel 3: CLL max-sim per (b,c) pair ----------------
// v_pat_c (196x96) staged in LDS once per block; padded tiles clamp to row 195
// (duplicated valid rows can't change the max). Block max -> S_CLL.

__global__ __launch_bounds__(256, 3) void cll_kernel(
    const bf16* __restrict__ Tt, const bf16* __restrict__ Vp, float* __restrict__ S_CLL)
{
    int b = blockIdx.x >> 6, c = blockIdx.x & 63;
    int tid = threadIdx.x, lane = tid & 63, w = tid >> 6;
    int m = lane & 15, quad = lane >> 4;
    const bf16* T = Tt + (size_t)b * (128 * 96);
    const bf16* P = Vp + (size_t)c * (196 * 96);

    __shared__ __align__(16) bf16 Plds[196 * 96];
    for (int ch = tid; ch < 2352; ch += 256)
        *(uint4v*)(Plds + ch * 8) = *(const uint4v*)(P + ch * 8);
    __syncthreads();

    int rofs[13];
    #pragma unroll
    for (int nt = 0; nt < 13; nt++) {
        int r = nt * 16 + m; if (r > 195) r = 195;
        rofs[nt] = r * 96;
    }
    f32x4 acc[2][13] = {};
    #pragma unroll
    for (int kk = 0; kk < 96; kk += 32) {
        bf16x8 a0 = *(const bf16x8*)(T + (size_t)(w * 32 + m) * 96 + kk + quad * 8);
        bf16x8 a1 = *(const bf16x8*)(T + (size_t)(w * 32 + 16 + m) * 96 + kk + quad * 8);
        #pragma unroll
        for (int nt = 0; nt < 13; nt++) {
            bf16x8 bb = *(const bf16x8*)(Plds + rofs[nt] + kk + quad * 8);
            acc[0][nt] = MFMA16(a0, bb, acc[0][nt]);
            acc[1][nt] = MFMA16(a1, bb, acc[1][nt]);
        }
    }
    float mx = -3.4e38f;
    #pragma unroll
    for (int mt = 0; mt < 2; mt++)
        #pragma unroll
        for (int nt = 0; nt < 13; nt++)
            #pragma unroll
            for (int r = 0; r < 4; r++) mx = fmaxf(mx, acc[mt][nt][r]);
    #pragma unroll
    for (int d = 1; d < 64; d <<= 1) mx = fmaxf(mx, __shfl_xor(mx, d));
    __shared__ float red[4];
    if (lane == 0) red[w] = mx;
    __syncthreads();
    if (tid == 0) S_CLL[blockIdx.x] = fmaxf(fmaxf(red[0], red[1]), fmaxf(red[2], red[3]));
}

// ---------------- Kernel 4: final combine ----------------

__global__ __launch_bounds__(64) void final_kernel(
    const float* __restrict__ t, const float* __restrict__ d, const float* __restrict__ v,
    const float* __restrict__ S_TGL, const float* __restrict__ S_CLL, float* __restrict__ out)
{
    int i = blockIdx.x, j = threadIdx.x;
    __shared__ float ti[96];
    if (j < 64) ti[j] = t[i * 96 + j];
    if (j < 32) ti[64 + j] = t[i * 96 + 64 + j];
    __syncthreads();
    float tg = 0.0f, cg = 0.0f;
    const float* dj = d + j * 96;
    const float* vj = v + j * 96;
    #pragma unroll 8
    for (int h = 0; h < 96; h++) { float th = ti[h]; tg += th * dj[h]; cg += th * vj[h]; }
    float res = 0.5f * (tg + S_TGL[i * 64 + j]) + 0.5f * (cg + S_CLL[i * 64 + j]);
    out[i * 64 + j] = res;
}

// ---------------- launch ----------------

extern "C" void kernel_launch(void* const* d_in, const int* in_sizes, int n_in,
                              void* d_out, int out_size, void* d_ws, size_t ws_size,
                              hipStream_t stream)
{
    (void)in_sizes; (void)n_in; (void)out_size; (void)ws_size;
    const float* z_d_cls   = (const float*)d_in[0];
    const float* Z_d_tok   = (const float*)d_in[1];
    const float* z_t_cls   = (const float*)d_in[2];
    const float* Z_t_tok   = (const float*)d_in[3];
    const float* z_v_cls   = (const float*)d_in[4];
    const float* Z_v_patch = (const float*)d_in[5];

    char* ws = (char*)d_ws;
    float* t     = (float*)(ws + 0);               // 64*96 f32
    float* d     = (float*)(ws + 24576);
    float* v     = (float*)(ws + 49152);
    float* S_TGL = (float*)(ws + 73728);           // 4096 f32
    float* S_CLL = (float*)(ws + 90112);
    bf16* Wb = (bf16*)(ws + 106496);               // 8*96*512 bf16 = 786432 B
    bf16* Qb = (bf16*)(ws + 892928);               // 8192*96 bf16 = 1572864 B
    bf16* Kb = (bf16*)(ws + 892928 + 1572864);
    bf16* Vb = (bf16*)(ws + 892928 + 2 * 1572864);
    bf16* Tt = (bf16*)(ws + 892928 + 3 * 1572864);
    bf16* Vp = (bf16*)(ws + 892928 + 4 * 1572864); // 12544*96 bf16 = 2408448 B

    // W order matches proj job order: t,d,v,Q,K,V,t_tok,v_pat
    WPtrs wp;
    wp.W[0] = (const float*)d_in[6];   // W_t_cls
    wp.W[1] = (const float*)d_in[8];   // W_d_cls
    wp.W[2] = (const float*)d_in[10];  // W_v_cls
    wp.W[3] = (const float*)d_in[16];  // W_tgl_q
    wp.W[4] = (const float*)d_in[18];  // W_tgl_k
    wp.W[5] = (const float*)d_in[20];  // W_tgl_v
    wp.W[6] = (const float*)d_in[12];  // W_t_tok
    wp.W[7] = (const float*)d_in[14];  // W_v_patch
    hipLaunchKernelGGL(cvtw_kernel, dim3(384), dim3(256), 0, stream, wp, Wb);

    ProjParams pp;
    pp.Wb = Wb;
    pp.src[0] = z_t_cls;   pp.B[0] = (const float*)d_in[7];  pp.dst[0] = t;
    pp.src[1] = z_d_cls;   pp.B[1] = (const float*)d_in[9];  pp.dst[1] = d;
    pp.src[2] = z_v_cls;   pp.B[2] = (const float*)d_in[11]; pp.dst[2] = v;
    pp.src[3] = Z_d_tok;   pp.B[3] = (const float*)d_in[17]; pp.dst[3] = Qb;
    pp.src[4] = Z_t_tok;   pp.B[4] = (const float*)d_in[19]; pp.dst[4] = Kb;
    pp.src[5] = Z_t_tok;   pp.B[5] = (const float*)d_in[21]; pp.dst[5] = Vb;
    pp.src[6] = Z_t_tok;   pp.B[6] = (const float*)d_in[13]; pp.dst[6] = Tt;
    pp.src[7] = Z_v_patch; pp.B[7] = (const float*)d_in[15]; pp.dst[7] = Vp;
    hipLaunchKernelGGL(proj_kernel, dim3(356), dim3(256), 0, stream, pp);

    hipLaunchKernelGGL(attn_kernel, dim3(4096), dim3(256), 0, stream,
                       (const bf16*)Qb, (const bf16*)Kb, (const bf16*)Vb,
                       (const float*)d, (const float*)d_in[22], (const float*)d_in[23], S_TGL);
    hipLaunchKernelGGL(cll_kernel, dim3(4096), dim3(256), 0, stream,
                       (const bf16*)Tt, (const bf16*)Vp, S_CLL);
    hipLaunchKernelGGL(final_kernel, dim3(64), dim3(64), 0, stream,
                       (const float*)t, (const float*)d, (const float*)v,
                       (const float*)S_TGL, (const float*)S_CLL, (float*)d_out);
}

// Round 4
// 243.897 us; speedup vs baseline: 1.3101x; 1.0417x over previous
//
#include <hip/hip_runtime.h>
#include <hip/hip_bf16.h>

typedef __bf16 bf16;
typedef __attribute__((ext_vector_type(8))) __bf16 bf16x8;
typedef __attribute__((ext_vector_type(4))) float f32x4;
typedef __attribute__((ext_vector_type(4))) unsigned int uint4v;

#define MFMA16(a, b, c) __builtin_amdgcn_mfma_f32_16x16x32_bf16(a, b, c, 0, 0, 0)

__device__ inline bf16x8 cvt8(const float* p) {
    f32x4 lo = *(const f32x4*)p;
    f32x4 hi = *(const f32x4*)(p + 4);
    bf16x8 r;
    r[0] = (bf16)lo[0]; r[1] = (bf16)lo[1]; r[2] = (bf16)lo[2]; r[3] = (bf16)lo[3];
    r[4] = (bf16)hi[0]; r[5] = (bf16)hi[1]; r[6] = (bf16)hi[2]; r[7] = (bf16)hi[3];
    return r;
}

// ---------------- Kernel 0: convert all 8 weight matrices fp32 -> bf16 ----------------

struct WPtrs { const float* W[8]; };

__global__ __launch_bounds__(256) void cvtw_kernel(WPtrs wp, bf16* __restrict__ Wb) {
    int j   = blockIdx.x / 48;
    int blk = blockIdx.x - j * 48;
    int idx = (blk * 256 + threadIdx.x) * 4;
    f32x4 v = *(const f32x4*)(wp.W[j] + idx);
    bf16* dst = Wb + j * 49152 + idx;
    dst[0] = (bf16)v[0]; dst[1] = (bf16)v[1]; dst[2] = (bf16)v[2]; dst[3] = (bf16)v[3];
}

// ---------------- Kernel 1: all 8 projections (x @ W^T + b, optional l2norm) ----------
// Block = 128 threads = 2 waves; block covers 32 rows x 96 cols.
// Wave nh covers cols [nh*48, nh*48+48) (3 16x16 N-tiles) -> per-iter 4 A-loads +
// 3 B-loads + 6 MFMA, 2844 waves over 1422 blocks (load balance + TLP).
// l2norm needs full-row sum(x^2): the two waves exchange partials via LDS.

struct ProjParams {
    const float* src[8];
    const float* B[8];
    void* dst[8];
    const bf16* Wb;
};

__global__ __launch_bounds__(128, 8) void proj_kernel(ProjParams p) {
    int g   = blockIdx.x;
    int tid = threadIdx.x;
    int nh = tid >> 6, lane = tid & 63;
    int m = lane & 15, quad = lane >> 4;

    // jobs: 0:t 1:d 2:v 3:Q 4:K 5:V 6:t_tok 7:v_pat
    // 32-row groups: 2,2,2,256,256,256,256,392 ; cum: 2,4,6,262,518,774,1030,1422
    int job = 0, base = 0;
    if (g >= 2)    { job = 1; base = 2; }
    if (g >= 4)    { job = 2; base = 4; }
    if (g >= 6)    { job = 3; base = 6; }
    if (g >= 262)  { job = 4; base = 262; }
    if (g >= 518)  { job = 5; base = 518; }
    if (g >= 774)  { job = 6; base = 774; }
    if (g >= 1030) { job = 7; base = 1030; }
    int r0 = (g - base) << 5;

    const float* X  = p.src[job];
    const bf16*  wb = p.Wb + job * 49152 + (size_t)(nh * 48 + m) * 512 + quad * 8;
    const float* x0 = X + (size_t)(r0 + m) * 512 + quad * 8;
    const float* x1 = x0 + 16 * 512;

    f32x4 acc[2][3] = {};
    #pragma unroll 4
    for (int kk = 0; kk < 512; kk += 32) {
        bf16x8 a0 = cvt8(x0 + kk);
        bf16x8 a1 = cvt8(x1 + kk);
        #pragma unroll
        for (int nt = 0; nt < 3; nt++) {
            bf16x8 b = *(const bf16x8*)(wb + nt * 8192 + kk);
            acc[0][nt] = MFMA16(a0, b, acc[0][nt]);
            acc[1][nt] = MFMA16(a1, b, acc[1][nt]);
        }
    }
    const float* Bv = p.B[job];
    #pragma unroll
    for (int t2 = 0; t2 < 2; t2++)
        #pragma unroll
        for (int nt = 0; nt < 3; nt++) {
            float bb = Bv[nh * 48 + nt * 16 + m];
            acc[t2][nt][0] += bb; acc[t2][nt][1] += bb;
            acc[t2][nt][2] += bb; acc[t2][nt][3] += bb;
        }

    bool norm = (job < 3) || (job >= 6);
    __shared__ float sx[2][2][16];   // [nh][t2][quad*4+r]
    if (norm) {
        float ss[2][4];
        #pragma unroll
        for (int t2 = 0; t2 < 2; t2++)
            #pragma unroll
            for (int r = 0; r < 4; r++) {
                float s = 0.0f;
                #pragma unroll
                for (int nt = 0; nt < 3; nt++) s += acc[t2][nt][r] * acc[t2][nt][r];
                s += __shfl_xor(s, 1); s += __shfl_xor(s, 2);
                s += __shfl_xor(s, 4); s += __shfl_xor(s, 8);
                ss[t2][r] = s;
            }
        if (m == 0) {
            #pragma unroll
            for (int t2 = 0; t2 < 2; t2++)
                #pragma unroll
                for (int r = 0; r < 4; r++)
                    sx[nh][t2][quad * 4 + r] = ss[t2][r];
        }
        __syncthreads();
        #pragma unroll
        for (int t2 = 0; t2 < 2; t2++)
            #pragma unroll
            for (int r = 0; r < 4; r++) {
                float tot = ss[t2][r] + sx[1 - nh][t2][quad * 4 + r];
                float inv = 1.0f / fmaxf(sqrtf(tot), 1e-6f);
                #pragma unroll
                for (int nt = 0; nt < 3; nt++) acc[t2][nt][r] *= inv;
            }
    }
    if (job < 3) {
        float* dst = (float*)p.dst[job];
        #pragma unroll
        for (int t2 = 0; t2 < 2; t2++)
            #pragma unroll
            for (int r = 0; r < 4; r++)
                #pragma unroll
                for (int nt = 0; nt < 3; nt++)
                    dst[(size_t)(r0 + t2 * 16 + quad * 4 + r) * 96 + nh * 48 + nt * 16 + m] = acc[t2][nt][r];
    } else {
        bf16* dst = (bf16*)p.dst[job];
        #pragma unroll
        for (int t2 = 0; t2 < 2; t2++)
            #pragma unroll
            for (int r = 0; r < 4; r++)
                #pragma unroll
                for (int nt = 0; nt < 3; nt++)
                    dst[(size_t)(r0 + t2 * 16 + quad * 4 + r) * 96 + nh * 48 + nt * 16 + m] = (bf16)acc[t2][nt][r];
    }
}

// ---------------- Kernel 2: TGL attention per (b,c) pair ----------------
// K_c staged in LDS (rows padded 96->104 bf16: 8-way -> 2-way bank conflicts).
// S = Q_b K_c^T / sqrt(96); softmax over k; w[k] = sum_q attn[q,k];
// ctx[h] = (1/128) sum_k w[k] V_c[k,h] (vectorized 4-wave matvec); LN; l2n; dot d_b.

__global__ __launch_bounds__(256) void attn_kernel(
    const bf16* __restrict__ Qg, const bf16* __restrict__ Kg, const bf16* __restrict__ Vg,
    const float* __restrict__ dvec, const float* __restrict__ ln_g, const float* __restrict__ ln_b,
    float* __restrict__ S_TGL)
{
    int b = blockIdx.x >> 6, c = blockIdx.x & 63;
    int tid = threadIdx.x, lane = tid & 63, w = tid >> 6;
    int m = lane & 15, quad = lane >> 4;
    const bf16* Q = Qg + (size_t)b * (128 * 96);
    const bf16* K = Kg + (size_t)c * (128 * 96);
    const bf16* V = Vg + (size_t)c * (128 * 96);

    __shared__ __align__(16) bf16 Klds[128 * 104];
    #pragma unroll
    for (int it = 0; it < 6; it++) {
        int ch = it * 256 + tid;              // 1536 chunks of 8 elems
        int row = ch / 12, seg = ch - row * 12;
        *(uint4v*)(Klds + row * 104 + seg * 8) = *(const uint4v*)(K + ch * 8);
    }
    __syncthreads();

    f32x4 acc[2][8] = {};
    #pragma unroll
    for (int kk = 0; kk < 96; kk += 32) {
        bf16x8 a0 = *(const bf16x8*)(Q + (size_t)(w * 32 + m) * 96 + kk + quad * 8);
        bf16x8 a1 = *(const bf16x8*)(Q + (size_t)(w * 32 + 16 + m) * 96 + kk + quad * 8);
        #pragma unroll
        for (int nt = 0; nt < 8; nt++) {
            bf16x8 bb = *(const bf16x8*)(Klds + (nt * 16 + m) * 104 + kk + quad * 8);
            acc[0][nt] = MFMA16(a0, bb, acc[0][nt]);
            acc[1][nt] = MFMA16(a1, bb, acc[1][nt]);
        }
    }
    const float sc = 0.10206207261596575f;  // 1/sqrt(96)
    float wpart[8];
    #pragma unroll
    for (int nt = 0; nt < 8; nt++) wpart[nt] = 0.0f;
    #pragma unroll
    for (int mt = 0; mt < 2; mt++) {
        #pragma unroll
        for (int r = 0; r < 4; r++) {
            float tv[8]; float mx = -3.4e38f;
            #pragma unroll
            for (int nt = 0; nt < 8; nt++) { tv[nt] = acc[mt][nt][r] * sc; mx = fmaxf(mx, tv[nt]); }
            mx = fmaxf(mx, __shfl_xor(mx, 1)); mx = fmaxf(mx, __shfl_xor(mx, 2));
            mx = fmaxf(mx, __shfl_xor(mx, 4)); mx = fmaxf(mx, __shfl_xor(mx, 8));
            float s = 0.0f;
            #pragma unroll
            for (int nt = 0; nt < 8; nt++) { tv[nt] = __expf(tv[nt] - mx); s += tv[nt]; }
            s += __shfl_xor(s, 1); s += __shfl_xor(s, 2);
            s += __shfl_xor(s, 4); s += __shfl_xor(s, 8);
            float inv = 1.0f / s;
            #pragma unroll
            for (int nt = 0; nt < 8; nt++) wpart[nt] += tv[nt] * inv;
        }
    }
    #pragma unroll
    for (int nt = 0; nt < 8; nt++) {
        wpart[nt] += __shfl_xor(wpart[nt], 16);
        wpart[nt] += __shfl_xor(wpart[nt], 32);
    }
    __shared__ float wsum4[4][128];
    __shared__ float wk[128];
    __shared__ float ctxp[4][96];
    __shared__ float ctx[96];
    if (lane < 16) {
        #pragma unroll
        for (int nt = 0; nt < 8; nt++) wsum4[w][nt * 16 + lane] = wpart[nt];
    }
    __syncthreads();
    if (tid < 128) wk[tid] = wsum4[0][tid] + wsum4[1][tid] + wsum4[2][tid] + wsum4[3][tid];
    __syncthreads();
    // ctx matvec: wave w covers k in [w*32, w*32+32); lanes<48 read V pairs coalesced.
    {
        float c0 = 0.0f, c1 = 0.0f;
        if (lane < 48) {
            #pragma unroll 4
            for (int r = 0; r < 32; r++) {
                int k = w * 32 + r;
                unsigned u = *(const unsigned*)(V + (size_t)k * 96 + lane * 2);
                float lo = __uint_as_float(u << 16);
                float hi = __uint_as_float(u & 0xffff0000u);
                float wkk = wk[k];
                c0 += wkk * lo; c1 += wkk * hi;
            }
            ctxp[w][lane * 2]     = c0;
            ctxp[w][lane * 2 + 1] = c1;
        }
    }
    __syncthreads();
    if (tid < 96) ctx[tid] = (ctxp[0][tid] + ctxp[1][tid] + ctxp[2][tid] + ctxp[3][tid]) * (1.0f / 128.0f);
    __syncthreads();
    if (w == 0) {
        float x0 = ctx[lane];
        float x1 = (lane < 32) ? ctx[64 + lane] : 0.0f;
        float s = x0 + x1;
        #pragma unroll
        for (int d = 1; d < 64; d <<= 1) s += __shfl_xor(s, d);
        float mean = s * (1.0f / 96.0f);
        float e0 = x0 - mean;
        float e1 = (lane < 32) ? (x1 - mean) : 0.0f;
        float q = e0 * e0 + e1 * e1;
        #pragma unroll
        for (int d = 1; d < 64; d <<= 1) q += __shfl_xor(q, d);
        float rstd = rsqrtf(q * (1.0f / 96.0f) + 1e-5f);
        float y0 = e0 * rstd * ln_g[lane] + ln_b[lane];
        float y1 = 0.0f;
        if (lane < 32) y1 = e1 * rstd * ln_g[64 + lane] + ln_b[64 + lane];
        const float* db = dvec + b * 96;
        float dot = y0 * db[lane] + ((lane < 32) ? y1 * db[64 + lane] : 0.0f);
        float ss = y0 * y0 + y1 * y1;
        #pragma unroll
        for (int d = 1; d < 64; d <<= 1) { dot += __shfl_xor(dot, d); ss += __shfl_xor(ss, d); }
        if (lane == 0) S_TGL[blockIdx.x] = dot / fmaxf(sqrtf(ss), 1e-6f);
    }
}

// ---------------- Kernel 3: CLL max-sim per (b,c) pair ----------------
// v_pat_c staged in LDS (rows padded 96->104); padded row-tiles clamp to row 195.

__global__ __launch_bounds__(256) void cll_kernel(
    const bf16* __restrict__ Tt, const bf16* __restrict__ Vp, float* __restrict__ S_CLL)
{
    int b = blockIdx.x >> 6, c = blockIdx.x & 63;
    int tid = threadIdx.x, lane = tid & 63, w = tid >> 6;
    int m = lane & 15, quad = lane >> 4;
    const bf16* T = Tt + (size_t)b * (128 * 96);
    const bf16* P = Vp + (size_t)c * (196 * 96);

    __shared__ __align__(16) bf16 Plds[196 * 104];
    for (int ch = tid; ch < 2352; ch += 256) {
        int row = ch / 12, seg = ch - row * 12;
        *(uint4v*)(Plds + row * 104 + seg * 8) = *(const uint4v*)(P + ch * 8);
    }
    __syncthreads();

    int rofs[13];
    #pragma unroll
    for (int nt = 0; nt < 13; nt++) {
        int r = nt * 16 + m; if (r > 195) r = 195;
        rofs[nt] = r * 104;
    }
    f32x4 acc[2][13] = {};
    #pragma unroll
    for (int kk = 0; kk < 96; kk += 32) {
        bf16x8 a0 = *(const bf16x8*)(T + (size_t)(w * 32 + m) * 96 + kk + quad * 8);
        bf16x8 a1 = *(const bf16x8*)(T + (size_t)(w * 32 + 16 + m) * 96 + kk + quad * 8);
        #pragma unroll
        for (int nt = 0; nt < 13; nt++) {
            bf16x8 bb = *(const bf16x8*)(Plds + rofs[nt] + kk + quad * 8);
            acc[0][nt] = MFMA16(a0, bb, acc[0][nt]);
            acc[1][nt] = MFMA16(a1, bb, acc[1][nt]);
        }
    }
    float mx = -3.4e38f;
    #pragma unroll
    for (int mt = 0; mt < 2; mt++)
        #pragma unroll
        for (int nt = 0; nt < 13; nt++)
            #pragma unroll
            for (int r = 0; r < 4; r++) mx = fmaxf(mx, acc[mt][nt][r]);
    #pragma unroll
    for (int d = 1; d < 64; d <<= 1) mx = fmaxf(mx, __shfl_xor(mx, d));
    __shared__ float red[4];
    if (lane == 0) red[w] = mx;
    __syncthreads();
    if (tid == 0) S_CLL[blockIdx.x] = fmaxf(fmaxf(red[0], red[1]), fmaxf(red[2], red[3]));
}

// ---------------- Kernel 4: final combine ----------------

__global__ __launch_bounds__(64) void final_kernel(
    const float* __restrict__ t, const float* __restrict__ d, const float* __restrict__ v,
    const float* __restrict__ S_TGL, const float* __restrict__ S_CLL, float* __restrict__ out)
{
    int i = blockIdx.x, j = threadIdx.x;
    __shared__ float ti[96];
    if (j < 64) ti[j] = t[i * 96 + j];
    if (j < 32) ti[64 + j] = t[i * 96 + 64 + j];
    __syncthreads();
    float tg = 0.0f, cg = 0.0f;
    const float* dj = d + j * 96;
    const float* vj = v + j * 96;
    #pragma unroll 8
    for (int h = 0; h < 96; h++) { float th = ti[h]; tg += th * dj[h]; cg += th * vj[h]; }
    float res = 0.5f * (tg + S_TGL[i * 64 + j]) + 0.5f * (cg + S_CLL[i * 64 + j]);
    out[i * 64 + j] = res;
}

// ---------------- launch ----------------

extern "C" void kernel_launch(void* const* d_in, const int* in_sizes, int n_in,
                              void* d_out, int out_size, void* d_ws, size_t ws_size,
                              hipStream_t stream)
{
    (void)in_sizes; (void)n_in; (void)out_size; (void)ws_size;
    const float* z_d_cls   = (const float*)d_in[0];
    const float* Z_d_tok   = (const float*)d_in[1];
    const float* z_t_cls   = (const float*)d_in[2];
    const float* Z_t_tok   = (const float*)d_in[3];
    const float* z_v_cls   = (const float*)d_in[4];
    const float* Z_v_patch = (const float*)d_in[5];

    char* ws = (char*)d_ws;
    float* t     = (float*)(ws + 0);               // 64*96 f32
    float* d     = (float*)(ws + 24576);
    float* v     = (float*)(ws + 49152);
    float* S_TGL = (float*)(ws + 73728);           // 4096 f32
    float* S_CLL = (float*)(ws + 90112);
    bf16* Wb = (bf16*)(ws + 106496);               // 8*96*512 bf16 = 786432 B
    bf16* Qb = (bf16*)(ws + 892928);               // 8192*96 bf16 = 1572864 B
    bf16* Kb = (bf16*)(ws + 892928 + 1572864);
    bf16* Vb = (bf16*)(ws + 892928 + 2 * 1572864);
    bf16* Tt = (bf16*)(ws + 892928 + 3 * 1572864);
    bf16* Vp = (bf16*)(ws + 892928 + 4 * 1572864); // 12544*96 bf16 = 2408448 B

    WPtrs wp;
    wp.W[0] = (const float*)d_in[6];   // W_t_cls
    wp.W[1] = (const float*)d_in[8];   // W_d_cls
    wp.W[2] = (const float*)d_in[10];  // W_v_cls
    wp.W[3] = (const float*)d_in[16];  // W_tgl_q
    wp.W[4] = (const float*)d_in[18];  // W_tgl_k
    wp.W[5] = (const float*)d_in[20];  // W_tgl_v
    wp.W[6] = (const float*)d_in[12];  // W_t_tok
    wp.W[7] = (const float*)d_in[14];  // W_v_patch
    hipLaunchKernelGGL(cvtw_kernel, dim3(384), dim3(256), 0, stream, wp, Wb);

    ProjParams pp;
    pp.Wb = Wb;
    pp.src[0] = z_t_cls;   pp.B[0] = (const float*)d_in[7];  pp.dst[0] = t;
    pp.src[1] = z_d_cls;   pp.B[1] = (const float*)d_in[9];  pp.dst[1] = d;
    pp.src[2] = z_v_cls;   pp.B[2] = (const float*)d_in[11]; pp.dst[2] = v;
    pp.src[3] = Z_d_tok;   pp.B[3] = (const float*)d_in[17]; pp.dst[3] = Qb;
    pp.src[4] = Z_t_tok;   pp.B[4] = (const float*)d_in[19]; pp.dst[4] = Kb;
    pp.src[5] = Z_t_tok;   pp.B[5] = (const float*)d_in[21]; pp.dst[5] = Vb;
    pp.src[6] = Z_t_tok;   pp.B[6] = (const float*)d_in[13]; pp.dst[6] = Tt;
    pp.src[7] = Z_v_patch; pp.B[7] = (const float*)d_in[15]; pp.dst[7] = Vp;
    hipLaunchKernelGGL(proj_kernel, dim3(1422), dim3(128), 0, stream, pp);

    hipLaunchKernelGGL(attn_kernel, dim3(4096), dim3(256), 0, stream,
                       (const bf16*)Qb, (const bf16*)Kb, (const bf16*)Vb,
                       (const float*)d, (const float*)d_in[22], (const float*)d_in[23], S_TGL);
    hipLaunchKernelGGL(cll_kernel, dim3(4096), dim3(256), 0, stream,
                       (const bf16*)Tt, (const bf16*)Vp, S_CLL);
    hipLaunchKernelGGL(final_kernel, dim3(64), dim3(64), 0, stream,
                       (const float*)t, (const float*)d, (const float*)v,
                       (const float*)S_TGL, (const float*)S_CLL, (float*)d_out);
}